// Round 1
// baseline (1509.369 us; speedup 1.0000x reference)
//
#include <hip/hip_runtime.h>
#include <hip/hip_bf16.h>

// ---------------------------------------------------------------------------
// GraphChebNet: 3-layer ChebConv (K=2) on N=50000 nodes, E=400000 edges.
//   norm: deg = sum over edges (src!=dst) by src; dinv = rsqrt(deg) or 0
//         w[e] = -dinv[src]*dinv[dst]*(src!=dst)
//   layer: tx = segment_sum(w * x[src], dst);  out = relu?(x@W0 + tx@W1 + b)
// Round 1: correctness-first fp32. Scatter via global fp32 atomics (working
// set fits L3). GEMM: classic 64x64 LDS-tiled SGEMM, fused X@W0 + T@W1 + b.
// ---------------------------------------------------------------------------

__global__ __launch_bounds__(256) void deg_kernel(const int* __restrict__ src,
                                                  const int* __restrict__ dst,
                                                  float* __restrict__ deg, int E) {
    int e = blockIdx.x * blockDim.x + threadIdx.x;
    if (e < E) {
        int s = src[e];
        if (s != dst[e]) atomicAdd(&deg[s], 1.0f);
    }
}

__global__ __launch_bounds__(256) void dinv_kernel(float* __restrict__ deg, int N) {
    int i = blockIdx.x * blockDim.x + threadIdx.x;
    if (i < N) {
        float d = deg[i];
        deg[i] = (d > 0.0f) ? rsqrtf(d) : 0.0f;   // in-place: deg -> dinv
    }
}

__global__ __launch_bounds__(256) void w_kernel(const int* __restrict__ src,
                                                const int* __restrict__ dst,
                                                const float* __restrict__ dinv,
                                                float* __restrict__ w, int E) {
    int e = blockIdx.x * blockDim.x + threadIdx.x;
    if (e < E) {
        int s = src[e], d = dst[e];
        w[e] = (s != d) ? (-dinv[s] * dinv[d]) : 0.0f;
    }
}

// tx[dst] += w * x[src], one thread per (edge, feature) element.
template <int F>
__global__ __launch_bounds__(256) void scatter_kernel(const int* __restrict__ src,
                                                      const int* __restrict__ dst,
                                                      const float* __restrict__ w,
                                                      const float* __restrict__ x,
                                                      float* __restrict__ tx, int E) {
    constexpr int LOG2F = (F == 128) ? 7 : 8;
    long long idx = (long long)blockIdx.x * blockDim.x + threadIdx.x;
    if (idx >= (long long)E * F) return;
    int e = (int)(idx >> LOG2F);
    int f = (int)(idx & (F - 1));
    float wv = w[e];
    if (wv == 0.0f) return;                        // self-loops / zero-deg
    int s = src[e], d = dst[e];
    atomicAdd(&tx[(long long)d * F + f], wv * x[(long long)s * F + f]);
}

// out[M,256] = relu?( X[M,K]@W0[K,256] + T[M,K]@W1[K,256] + b[256] )
// 64x64 tile per 256-thread block, 4x4 micro-tile per thread, BK=16.
template <int K, bool RELU>
__global__ __launch_bounds__(256) void gemm_fused(const float* __restrict__ X,
                                                  const float* __restrict__ T,
                                                  const float* __restrict__ W0,
                                                  const float* __restrict__ W1,
                                                  const float* __restrict__ b,
                                                  float* __restrict__ out, int M) {
    constexpr int BM = 64, BN = 64, BK = 16;
    __shared__ float As[BK][BM];
    __shared__ float Bs[BK][BN];

    const int tid = threadIdx.x;
    const int tx = tid & 15;        // 0..15 -> column group
    const int ty = tid >> 4;        // 0..15 -> row group
    const int row0 = blockIdx.x * BM;
    const int col0 = blockIdx.y * BN;

    // A-tile load mapping: 64 rows x 16 k, float4 along k
    const int am = tid >> 2;              // 0..63
    const int ak = (tid & 3) * 4;         // 0,4,8,12
    // B-tile load mapping: 16 k x 64 n, float4 along n
    const int bk = tid >> 4;              // 0..15
    const int bn = (tid & 15) * 4;        // 0..60

    float acc[4][4] = {};

    #pragma unroll
    for (int pass = 0; pass < 2; ++pass) {
        const float* Amat = pass ? T : X;
        const float* Wmat = pass ? W1 : W0;
        for (int k0 = 0; k0 < K; k0 += BK) {
            int arow = row0 + am;
            float4 av = make_float4(0.f, 0.f, 0.f, 0.f);
            if (arow < M)
                av = *reinterpret_cast<const float4*>(&Amat[(long long)arow * K + k0 + ak]);
            As[ak + 0][am] = av.x;
            As[ak + 1][am] = av.y;
            As[ak + 2][am] = av.z;
            As[ak + 3][am] = av.w;

            float4 bv = *reinterpret_cast<const float4*>(&Wmat[(long long)(k0 + bk) * 256 + col0 + bn]);
            *reinterpret_cast<float4*>(&Bs[bk][bn]) = bv;
            __syncthreads();

            #pragma unroll
            for (int k = 0; k < BK; ++k) {
                float a[4], bb[4];
                #pragma unroll
                for (int i = 0; i < 4; ++i) a[i] = As[k][ty * 4 + i];
                #pragma unroll
                for (int j = 0; j < 4; ++j) bb[j] = Bs[k][tx * 4 + j];
                #pragma unroll
                for (int i = 0; i < 4; ++i)
                    #pragma unroll
                    for (int j = 0; j < 4; ++j)
                        acc[i][j] += a[i] * bb[j];
            }
            __syncthreads();
        }
    }

    #pragma unroll
    for (int i = 0; i < 4; ++i) {
        int r = row0 + ty * 4 + i;
        if (r >= M) continue;
        #pragma unroll
        for (int j = 0; j < 4; ++j) {
            int c = col0 + tx * 4 + j;
            float v = acc[i][j] + b[c];
            if (RELU) v = fmaxf(v, 0.0f);
            out[(long long)r * 256 + c] = v;
        }
    }
}

static inline size_t align_up(size_t v, size_t a) { return (v + a - 1) / a * a; }

extern "C" void kernel_launch(void* const* d_in, const int* in_sizes, int n_in,
                              void* d_out, int out_size, void* d_ws, size_t ws_size,
                              hipStream_t stream) {
    const float* x    = (const float*)d_in[0];
    const int*   ei   = (const int*)d_in[1];
    const float* W1_0 = (const float*)d_in[2];
    const float* W1_1 = (const float*)d_in[3];
    const float* b1   = (const float*)d_in[4];
    const float* W2_0 = (const float*)d_in[5];
    const float* W2_1 = (const float*)d_in[6];
    const float* b2   = (const float*)d_in[7];
    const float* W3_0 = (const float*)d_in[8];
    const float* W3_1 = (const float*)d_in[9];
    const float* b3   = (const float*)d_in[10];
    float* out = (float*)d_out;

    const int N = in_sizes[0] / 128;
    const int E = in_sizes[1] / 2;
    const int* src = ei;
    const int* dst = ei + E;

    // workspace carve-up
    char* ws = (char*)d_ws;
    size_t off = 0;
    float* dinv = (float*)(ws + off); off = align_up(off + (size_t)N * 4, 256);          // deg -> dinv in place
    float* w    = (float*)(ws + off); off = align_up(off + (size_t)E * 4, 256);
    float* tx   = (float*)(ws + off); off = align_up(off + (size_t)N * 256 * 4, 256);
    float* h1   = (float*)(ws + off); off = align_up(off + (size_t)N * 256 * 4, 256);
    float* h2   = (float*)(ws + off); off = align_up(off + (size_t)N * 256 * 4, 256);
    (void)ws_size;

    const int TB = 256;
    dim3 gE((E + TB - 1) / TB);
    dim3 gN((N + TB - 1) / TB);

    // ---- norm precompute (shared by all 3 layers) ----
    hipMemsetAsync(dinv, 0, (size_t)N * 4, stream);
    deg_kernel<<<gE, TB, 0, stream>>>(src, dst, dinv, E);
    dinv_kernel<<<gN, TB, 0, stream>>>(dinv, N);
    w_kernel<<<gE, TB, 0, stream>>>(src, dst, dinv, w, E);

    dim3 gemmGrid((N + 63) / 64, 4);

    // ---- layer 1: F=128 ----
    hipMemsetAsync(tx, 0, (size_t)N * 128 * 4, stream);
    {
        long long tot = (long long)E * 128;
        dim3 gS((unsigned)((tot + TB - 1) / TB));
        scatter_kernel<128><<<gS, TB, 0, stream>>>(src, dst, w, x, tx, E);
    }
    gemm_fused<128, true><<<gemmGrid, TB, 0, stream>>>(x, tx, W1_0, W1_1, b1, h1, N);

    // ---- layer 2: F=256 ----
    hipMemsetAsync(tx, 0, (size_t)N * 256 * 4, stream);
    {
        long long tot = (long long)E * 256;
        dim3 gS((unsigned)((tot + TB - 1) / TB));
        scatter_kernel<256><<<gS, TB, 0, stream>>>(src, dst, w, h1, tx, E);
    }
    gemm_fused<256, true><<<gemmGrid, TB, 0, stream>>>(h1, tx, W2_0, W2_1, b2, h2, N);

    // ---- layer 3: F=256, no relu, write d_out ----
    hipMemsetAsync(tx, 0, (size_t)N * 256 * 4, stream);
    {
        long long tot = (long long)E * 256;
        dim3 gS((unsigned)((tot + TB - 1) / TB));
        scatter_kernel<256><<<gS, TB, 0, stream>>>(src, dst, w, h2, tx, E);
    }
    gemm_fused<256, false><<<gemmGrid, TB, 0, stream>>>(h2, tx, W3_0, W3_1, b3, out, N);
}

// Round 2
// 885.568 us; speedup vs baseline: 1.7044x; 1.7044x over previous
//
#include <hip/hip_runtime.h>
#include <hip/hip_bf16.h>

// ---------------------------------------------------------------------------
// GraphChebNet: 3-layer ChebConv (K=2), N=50000, E=400000.
// Round 2: kill the atomic scatter (409 MB HBM write-through per layer) with
// device-built CSR-by-dst + per-node register gather. GEMM unchanged (fp32,
// 64x64 tile, ~82 TF). CSR fill order is nondeterministic but only perturbs
// fp32 summation order (~1e-6 rel) — far under the 0.119 absmax threshold.
// ---------------------------------------------------------------------------

// deg (by src, excluding self-loops, float) + in-degree histogram (by dst, int)
__global__ __launch_bounds__(256) void deg_cnt_kernel(const int* __restrict__ src,
                                                      const int* __restrict__ dst,
                                                      float* __restrict__ deg,
                                                      int* __restrict__ cnt, int E) {
    int e = blockIdx.x * blockDim.x + threadIdx.x;
    if (e < E) {
        int s = src[e], d = dst[e];
        if (s != d) atomicAdd(&deg[s], 1.0f);
        atomicAdd(&cnt[d], 1);
    }
}

__global__ __launch_bounds__(256) void dinv_kernel(float* __restrict__ deg, int N) {
    int i = blockIdx.x * blockDim.x + threadIdx.x;
    if (i < N) {
        float d = deg[i];
        deg[i] = (d > 0.0f) ? rsqrtf(d) : 0.0f;   // in-place: deg -> dinv
    }
}

// ---- 3-kernel exclusive scan of cnt[N] -> rowptr[N+1], CHUNK=1024 ----
__global__ __launch_bounds__(256) void scan_partial(const int* __restrict__ cnt,
                                                    int* __restrict__ part, int N) {
    __shared__ int lds[256];
    int tid = threadIdx.x;
    int base = blockIdx.x * 1024 + tid * 4;
    int s = 0;
    #pragma unroll
    for (int i = 0; i < 4; ++i) if (base + i < N) s += cnt[base + i];
    lds[tid] = s;
    __syncthreads();
    for (int off = 128; off > 0; off >>= 1) {
        if (tid < off) lds[tid] += lds[tid + off];
        __syncthreads();
    }
    if (tid == 0) part[blockIdx.x] = lds[0];
}

__global__ __launch_bounds__(64) void scan_small(int* __restrict__ part, int NB,
                                                 int* __restrict__ rowptr, int N) {
    if (threadIdx.x == 0 && blockIdx.x == 0) {
        int total = 0;
        for (int i = 0; i < NB; ++i) { int t = part[i]; part[i] = total; total += t; }
        rowptr[N] = total;
    }
}

__global__ __launch_bounds__(256) void scan_chunk(const int* __restrict__ cnt,
                                                  const int* __restrict__ part,
                                                  int* __restrict__ rowptr, int N) {
    __shared__ int lds[256];
    int tid = threadIdx.x;
    int base = blockIdx.x * 1024 + tid * 4;
    int c[4];
    #pragma unroll
    for (int i = 0; i < 4; ++i) c[i] = (base + i < N) ? cnt[base + i] : 0;
    int ts = c[0] + c[1] + c[2] + c[3];
    lds[tid] = ts;
    __syncthreads();
    for (int off = 1; off < 256; off <<= 1) {
        int v = (tid >= off) ? lds[tid - off] : 0;
        __syncthreads();
        lds[tid] += v;
        __syncthreads();
    }
    int o = part[blockIdx.x] + lds[tid] - ts;   // exclusive prefix for this thread
    #pragma unroll
    for (int i = 0; i < 4; ++i) {
        if (base + i < N) rowptr[base + i] = o;
        o += c[i];
    }
}

// fill CSR: esrc/ew sorted by dst (order within a node nondeterministic)
__global__ __launch_bounds__(256) void fill_kernel(const int* __restrict__ src,
                                                   const int* __restrict__ dst,
                                                   const float* __restrict__ dinv,
                                                   int* __restrict__ cursor,
                                                   int* __restrict__ esrc,
                                                   float* __restrict__ ew, int E) {
    int e = blockIdx.x * blockDim.x + threadIdx.x;
    if (e < E) {
        int s = src[e], d = dst[e];
        int pos = atomicAdd(&cursor[d], 1);
        esrc[pos] = s;
        ew[pos] = (s != d) ? (-dinv[s] * dinv[d]) : 0.0f;
    }
}

// tx[n,f] = sum over in-edges of n: w * x[src, f].  One block per node,
// one thread per feature. Software-pipelined edge-meta loads.
template <int F>
__global__ __launch_bounds__(F) void gather_kernel(const int* __restrict__ rowptr,
                                                   const int* __restrict__ esrc,
                                                   const float* __restrict__ ew,
                                                   const float* __restrict__ x,
                                                   float* __restrict__ tx) {
    int n = blockIdx.x;
    int f = threadIdx.x;
    int beg = rowptr[n], end = rowptr[n + 1];
    float acc = 0.0f;
    int s_next = 0; float w_next = 0.0f;
    if (beg < end) { s_next = esrc[beg]; w_next = ew[beg]; }
    for (int k = beg; k < end; ++k) {
        int s = s_next; float wv = w_next;
        if (k + 1 < end) { s_next = esrc[k + 1]; w_next = ew[k + 1]; }
        acc += wv * x[(long long)s * F + f];
    }
    tx[(long long)n * F + f] = acc;
}

// out[M,256] = relu?( X[M,K]@W0[K,256] + T[M,K]@W1[K,256] + b[256] )
template <int K, bool RELU>
__global__ __launch_bounds__(256) void gemm_fused(const float* __restrict__ X,
                                                  const float* __restrict__ T,
                                                  const float* __restrict__ W0,
                                                  const float* __restrict__ W1,
                                                  const float* __restrict__ b,
                                                  float* __restrict__ out, int M) {
    constexpr int BM = 64, BN = 64, BK = 16;
    __shared__ float As[BK][BM];
    __shared__ float Bs[BK][BN];

    const int tid = threadIdx.x;
    const int tx = tid & 15;
    const int ty = tid >> 4;
    const int row0 = blockIdx.x * BM;
    const int col0 = blockIdx.y * BN;

    const int am = tid >> 2;
    const int ak = (tid & 3) * 4;
    const int bk = tid >> 4;
    const int bn = (tid & 15) * 4;

    float acc[4][4] = {};

    #pragma unroll
    for (int pass = 0; pass < 2; ++pass) {
        const float* Amat = pass ? T : X;
        const float* Wmat = pass ? W1 : W0;
        for (int k0 = 0; k0 < K; k0 += BK) {
            int arow = row0 + am;
            float4 av = make_float4(0.f, 0.f, 0.f, 0.f);
            if (arow < M)
                av = *reinterpret_cast<const float4*>(&Amat[(long long)arow * K + k0 + ak]);
            As[ak + 0][am] = av.x;
            As[ak + 1][am] = av.y;
            As[ak + 2][am] = av.z;
            As[ak + 3][am] = av.w;

            float4 bv = *reinterpret_cast<const float4*>(&Wmat[(long long)(k0 + bk) * 256 + col0 + bn]);
            *reinterpret_cast<float4*>(&Bs[bk][bn]) = bv;
            __syncthreads();

            #pragma unroll
            for (int k = 0; k < BK; ++k) {
                float a[4], bb[4];
                #pragma unroll
                for (int i = 0; i < 4; ++i) a[i] = As[k][ty * 4 + i];
                #pragma unroll
                for (int j = 0; j < 4; ++j) bb[j] = Bs[k][tx * 4 + j];
                #pragma unroll
                for (int i = 0; i < 4; ++i)
                    #pragma unroll
                    for (int j = 0; j < 4; ++j)
                        acc[i][j] += a[i] * bb[j];
            }
            __syncthreads();
        }
    }

    #pragma unroll
    for (int i = 0; i < 4; ++i) {
        int r = row0 + ty * 4 + i;
        if (r >= M) continue;
        #pragma unroll
        for (int j = 0; j < 4; ++j) {
            int c = col0 + tx * 4 + j;
            float v = acc[i][j] + b[c];
            if (RELU) v = fmaxf(v, 0.0f);
            out[(long long)r * 256 + c] = v;
        }
    }
}

static inline size_t align_up(size_t v, size_t a) { return (v + a - 1) / a * a; }

extern "C" void kernel_launch(void* const* d_in, const int* in_sizes, int n_in,
                              void* d_out, int out_size, void* d_ws, size_t ws_size,
                              hipStream_t stream) {
    const float* x    = (const float*)d_in[0];
    const int*   ei   = (const int*)d_in[1];
    const float* W1_0 = (const float*)d_in[2];
    const float* W1_1 = (const float*)d_in[3];
    const float* b1   = (const float*)d_in[4];
    const float* W2_0 = (const float*)d_in[5];
    const float* W2_1 = (const float*)d_in[6];
    const float* b2   = (const float*)d_in[7];
    const float* W3_0 = (const float*)d_in[8];
    const float* W3_1 = (const float*)d_in[9];
    const float* b3   = (const float*)d_in[10];
    float* out = (float*)d_out;

    const int N = in_sizes[0] / 128;
    const int E = in_sizes[1] / 2;
    const int* src = ei;
    const int* dst = ei + E;

    // workspace carve-up
    char* ws = (char*)d_ws;
    size_t off = 0;
    float* dinv   = (float*)(ws + off); off = align_up(off + (size_t)N * 4, 256);
    int*   cnt    = (int*)  (ws + off); off = align_up(off + (size_t)N * 4, 256);
    int*   rowptr = (int*)  (ws + off); off = align_up(off + (size_t)(N + 1) * 4, 256);
    int*   cursor = (int*)  (ws + off); off = align_up(off + (size_t)N * 4, 256);
    int*   part   = (int*)  (ws + off); off = align_up(off + 256 * 4, 256);
    int*   esrc   = (int*)  (ws + off); off = align_up(off + (size_t)E * 4, 256);
    float* ew     = (float*)(ws + off); off = align_up(off + (size_t)E * 4, 256);
    float* tx     = (float*)(ws + off); off = align_up(off + (size_t)N * 256 * 4, 256);
    float* h1     = (float*)(ws + off); off = align_up(off + (size_t)N * 256 * 4, 256);
    float* h2     = (float*)(ws + off); off = align_up(off + (size_t)N * 256 * 4, 256);
    (void)ws_size;

    const int TB = 256;
    dim3 gE((E + TB - 1) / TB);
    dim3 gN((N + TB - 1) / TB);
    const int NB = (N + 1023) / 1024;   // scan chunks

    // ---- norm + CSR build ----
    hipMemsetAsync(dinv, 0, (size_t)N * 4, stream);
    hipMemsetAsync(cnt, 0, (size_t)N * 4, stream);
    deg_cnt_kernel<<<gE, TB, 0, stream>>>(src, dst, dinv, cnt, E);
    dinv_kernel<<<gN, TB, 0, stream>>>(dinv, N);
    scan_partial<<<NB, 256, 0, stream>>>(cnt, part, N);
    scan_small<<<1, 64, 0, stream>>>(part, NB, rowptr, N);
    scan_chunk<<<NB, 256, 0, stream>>>(cnt, part, rowptr, N);
    hipMemcpyAsync(cursor, rowptr, (size_t)N * 4, hipMemcpyDeviceToDevice, stream);
    fill_kernel<<<gE, TB, 0, stream>>>(src, dst, dinv, cursor, esrc, ew, E);

    dim3 gemmGrid((N + 63) / 64, 4);

    // ---- layer 1: F=128 ----
    gather_kernel<128><<<N, 128, 0, stream>>>(rowptr, esrc, ew, x, tx);
    gemm_fused<128, true><<<gemmGrid, TB, 0, stream>>>(x, tx, W1_0, W1_1, b1, h1, N);

    // ---- layer 2: F=256 ----
    gather_kernel<256><<<N, 256, 0, stream>>>(rowptr, esrc, ew, h1, tx);
    gemm_fused<256, true><<<gemmGrid, TB, 0, stream>>>(h1, tx, W2_0, W2_1, b2, h2, N);

    // ---- layer 3: F=256, no relu ----
    gather_kernel<256><<<N, 256, 0, stream>>>(rowptr, esrc, ew, h2, tx);
    gemm_fused<256, false><<<gemmGrid, TB, 0, stream>>>(h2, tx, W3_0, W3_1, b3, out, N);
}

// Round 3
// 402.004 us; speedup vs baseline: 3.7546x; 2.2029x over previous
//
#include <hip/hip_runtime.h>
#include <hip/hip_bf16.h>

// ---------------------------------------------------------------------------
// GraphChebNet: 3-layer ChebConv (K=2), N=50000, E=400000.
// Round 3: bf16 MFMA GEMMs (16x16x32), bf16 feature matrices everywhere
// (halves gather traffic). Per-call prep: cast x -> bf16, cast+transpose
// weights -> WT[n][k] bf16 so A and B MFMA fragments are both contiguous-k
// 16B LDS reads. CSR-by-dst gather unchanged in structure, bf16 vectorized.
// ---------------------------------------------------------------------------

typedef __attribute__((ext_vector_type(8))) short bf16x8;
typedef __attribute__((ext_vector_type(4))) float f32x4;

__device__ __forceinline__ float bf2f(unsigned int lo16) {
    unsigned int t = lo16 << 16;
    return __builtin_bit_cast(float, t);
}
__device__ __forceinline__ unsigned short f2bf(float f) {
    unsigned int u = __builtin_bit_cast(unsigned int, f);
    unsigned int r = (u + 0x7fffu + ((u >> 16) & 1u)) >> 16;   // RNE
    return (unsigned short)r;
}

// ---------------- norm + CSR build (unchanged from round 2) ----------------
__global__ __launch_bounds__(256) void deg_cnt_kernel(const int* __restrict__ src,
                                                      const int* __restrict__ dst,
                                                      float* __restrict__ deg,
                                                      int* __restrict__ cnt, int E) {
    int e = blockIdx.x * blockDim.x + threadIdx.x;
    if (e < E) {
        int s = src[e], d = dst[e];
        if (s != d) atomicAdd(&deg[s], 1.0f);
        atomicAdd(&cnt[d], 1);
    }
}

__global__ __launch_bounds__(256) void dinv_kernel(float* __restrict__ deg, int N) {
    int i = blockIdx.x * blockDim.x + threadIdx.x;
    if (i < N) {
        float d = deg[i];
        deg[i] = (d > 0.0f) ? rsqrtf(d) : 0.0f;
    }
}

__global__ __launch_bounds__(256) void scan_partial(const int* __restrict__ cnt,
                                                    int* __restrict__ part, int N) {
    __shared__ int lds[256];
    int tid = threadIdx.x;
    int base = blockIdx.x * 1024 + tid * 4;
    int s = 0;
    #pragma unroll
    for (int i = 0; i < 4; ++i) if (base + i < N) s += cnt[base + i];
    lds[tid] = s;
    __syncthreads();
    for (int off = 128; off > 0; off >>= 1) {
        if (tid < off) lds[tid] += lds[tid + off];
        __syncthreads();
    }
    if (tid == 0) part[blockIdx.x] = lds[0];
}

__global__ __launch_bounds__(64) void scan_small(int* __restrict__ part, int NB,
                                                 int* __restrict__ rowptr, int N) {
    if (threadIdx.x == 0 && blockIdx.x == 0) {
        int total = 0;
        for (int i = 0; i < NB; ++i) { int t = part[i]; part[i] = total; total += t; }
        rowptr[N] = total;
    }
}

__global__ __launch_bounds__(256) void scan_chunk(const int* __restrict__ cnt,
                                                  const int* __restrict__ part,
                                                  int* __restrict__ rowptr, int N) {
    __shared__ int lds[256];
    int tid = threadIdx.x;
    int base = blockIdx.x * 1024 + tid * 4;
    int c[4];
    #pragma unroll
    for (int i = 0; i < 4; ++i) c[i] = (base + i < N) ? cnt[base + i] : 0;
    int ts = c[0] + c[1] + c[2] + c[3];
    lds[tid] = ts;
    __syncthreads();
    for (int off = 1; off < 256; off <<= 1) {
        int v = (tid >= off) ? lds[tid - off] : 0;
        __syncthreads();
        lds[tid] += v;
        __syncthreads();
    }
    int o = part[blockIdx.x] + lds[tid] - ts;
    #pragma unroll
    for (int i = 0; i < 4; ++i) {
        if (base + i < N) rowptr[base + i] = o;
        o += c[i];
    }
}

__global__ __launch_bounds__(256) void fill_kernel(const int* __restrict__ src,
                                                   const int* __restrict__ dst,
                                                   const float* __restrict__ dinv,
                                                   int* __restrict__ cursor,
                                                   int* __restrict__ esrc,
                                                   float* __restrict__ ew, int E) {
    int e = blockIdx.x * blockDim.x + threadIdx.x;
    if (e < E) {
        int s = src[e], d = dst[e];
        int pos = atomicAdd(&cursor[d], 1);
        esrc[pos] = s;
        ew[pos] = (s != d) ? (-dinv[s] * dinv[d]) : 0.0f;
    }
}

// ---------------- prep: casts ----------------
__global__ __launch_bounds__(256) void cast_x_kernel(const float* __restrict__ x,
                                                     unsigned short* __restrict__ xb,
                                                     long long n4) {   // n/4
    long long i = (long long)blockIdx.x * 256 + threadIdx.x;
    if (i >= n4) return;
    float4 v = reinterpret_cast<const float4*>(x)[i];
    ushort4 o;
    o.x = f2bf(v.x); o.y = f2bf(v.y); o.z = f2bf(v.z); o.w = f2bf(v.w);
    reinterpret_cast<ushort4*>(xb)[i] = o;
}

// W [K,256] fp32 -> WT [256,K] bf16 (k-contiguous rows)
__global__ __launch_bounds__(256) void transpose_cast(const float* __restrict__ W,
                                                      unsigned short* __restrict__ WT,
                                                      int K) {
    __shared__ float t[32][33];
    int kb = blockIdx.x * 32, nb = blockIdx.y * 32;
    int lx = threadIdx.x & 31, ly = threadIdx.x >> 5;   // 32 x 8
    #pragma unroll
    for (int i = 0; i < 32; i += 8)
        t[ly + i][lx] = W[(size_t)(kb + ly + i) * 256 + nb + lx];
    __syncthreads();
    #pragma unroll
    for (int i = 0; i < 32; i += 8)
        WT[(size_t)(nb + ly + i) * K + kb + lx] = f2bf(t[lx][ly + i]);
}

// ---------------- gather: tx[n,:] = sum_e w_e * x[src_e,:], bf16 ----------------
// one wave per node, lane handles V=F/64 features (bf16x2 / bf16x4).
template <int F>
__global__ __launch_bounds__(256) void gather_bf16(const int* __restrict__ rowptr,
                                                   const int* __restrict__ esrc,
                                                   const float* __restrict__ ew,
                                                   const unsigned short* __restrict__ xb,
                                                   unsigned short* __restrict__ txb,
                                                   int N) {
    constexpr int V = F / 64;   // 2 or 4
    int wave = threadIdx.x >> 6, lane = threadIdx.x & 63;
    int n = blockIdx.x * 4 + wave;
    if (n >= N) return;
    int beg = rowptr[n], end = rowptr[n + 1];
    float acc[V] = {};
    int s_next = 0; float w_next = 0.0f;
    if (beg < end) { s_next = esrc[beg]; w_next = ew[beg]; }
    for (int k = beg; k < end; ++k) {
        int s = s_next; float wv = w_next;
        if (k + 1 < end) { s_next = esrc[k + 1]; w_next = ew[k + 1]; }
        const unsigned short* p = &xb[(size_t)s * F + lane * V];
        if (V == 2) {
            unsigned int u = *reinterpret_cast<const unsigned int*>(p);
            acc[0] += wv * bf2f(u & 0xffffu);
            acc[1] += wv * bf2f(u >> 16);
        } else {
            uint2 u = *reinterpret_cast<const uint2*>(p);
            acc[0] += wv * bf2f(u.x & 0xffffu);
            acc[1] += wv * bf2f(u.x >> 16);
            acc[2] += wv * bf2f(u.y & 0xffffu);
            acc[3] += wv * bf2f(u.y >> 16);
        }
    }
    unsigned short* q = &txb[(size_t)n * F + lane * V];
    if (V == 2) {
        unsigned int o = (unsigned int)f2bf(acc[0]) | ((unsigned int)f2bf(acc[1]) << 16);
        *reinterpret_cast<unsigned int*>(q) = o;
    } else {
        uint2 o;
        o.x = (unsigned int)f2bf(acc[0]) | ((unsigned int)f2bf(acc[1]) << 16);
        o.y = (unsigned int)f2bf(acc[2]) | ((unsigned int)f2bf(acc[3]) << 16);
        *reinterpret_cast<uint2*>(q) = o;
    }
}

// ---------------- MFMA GEMM ----------------
// out[M,256] = relu?( Xb[M,K] @ W0 + Tb[M,K] @ W1 + b ), W given as WT[n][k] bf16.
// Block: 128x64 tile, 256 threads = 4 waves; wave w -> rows w*32..w*32+31,
// all 64 cols: 2x4 grid of 16x16 MFMA tiles. BK=64. LDS stride 72 shorts.
template <int K, bool RELU, typename OutT>
__global__ __launch_bounds__(256) void gemm_mfma(const unsigned short* __restrict__ Xb,
                                                 const unsigned short* __restrict__ Tb,
                                                 const unsigned short* __restrict__ W0T,
                                                 const unsigned short* __restrict__ W1T,
                                                 const float* __restrict__ bias,
                                                 OutT* __restrict__ out, int M) {
    constexpr int SA = 72;   // LDS row stride (shorts): 144B, 2-way bank alias = free
    __shared__ unsigned short As[128 * SA];
    __shared__ unsigned short Bs[64 * SA];

    const int tid = threadIdx.x;
    const int wave = tid >> 6;
    const int lane = tid & 63;
    const int l15 = lane & 15;
    const int quad = lane >> 4;
    const int row0 = blockIdx.x * 128;
    const int col0 = blockIdx.y * 64;

    // staging mapping: thread t, round r -> element block (r*256+t)*8
    const int srow = tid >> 3;          // 0..31 within a 256-thread round
    const int scol = (tid & 7) * 8;     // 0,8,...,56

    f32x4 acc[2][4];
    #pragma unroll
    for (int i = 0; i < 2; ++i)
        #pragma unroll
        for (int j = 0; j < 4; ++j) acc[i][j] = (f32x4){0.f, 0.f, 0.f, 0.f};

    #pragma unroll
    for (int pass = 0; pass < 2; ++pass) {
        const unsigned short* Amat = pass ? Tb : Xb;
        const unsigned short* Wmat = pass ? W1T : W0T;
        for (int k0 = 0; k0 < K; k0 += 64) {
            if (pass != 0 || k0 != 0) __syncthreads();   // protect LDS reuse
            // stage A: 128x64 bf16, 4 rounds of (32 rows x 64 k)
            #pragma unroll
            for (int r = 0; r < 4; ++r) {
                int row = r * 32 + srow;
                int grow = row0 + row; if (grow > M - 1) grow = M - 1;
                uint4 v = *reinterpret_cast<const uint4*>(&Amat[(size_t)grow * K + k0 + scol]);
                *reinterpret_cast<uint4*>(&As[row * SA + scol]) = v;
            }
            // stage B: 64x64 bf16, 2 rounds
            #pragma unroll
            for (int r = 0; r < 2; ++r) {
                int row = r * 32 + srow;   // n within tile
                uint4 v = *reinterpret_cast<const uint4*>(&Wmat[(size_t)(col0 + row) * K + k0 + scol]);
                *reinterpret_cast<uint4*>(&Bs[row * SA + scol]) = v;
            }
            __syncthreads();

            #pragma unroll
            for (int kf = 0; kf < 2; ++kf) {
                const int koff = kf * 32 + quad * 8;
                bf16x8 a[2], b[4];
                #pragma unroll
                for (int mt = 0; mt < 2; ++mt)
                    a[mt] = *reinterpret_cast<const bf16x8*>(
                        &As[(wave * 32 + mt * 16 + l15) * SA + koff]);
                #pragma unroll
                for (int nt = 0; nt < 4; ++nt)
                    b[nt] = *reinterpret_cast<const bf16x8*>(
                        &Bs[(nt * 16 + l15) * SA + koff]);
                #pragma unroll
                for (int mt = 0; mt < 2; ++mt)
                    #pragma unroll
                    for (int nt = 0; nt < 4; ++nt)
                        acc[mt][nt] = __builtin_amdgcn_mfma_f32_16x16x32_bf16(
                            a[mt], b[nt], acc[mt][nt], 0, 0, 0);
            }
        }
    }

    // epilogue: C/D layout col=lane&15, row=quad*4+reg  [m89-verified]
    #pragma unroll
    for (int mt = 0; mt < 2; ++mt) {
        #pragma unroll
        for (int r = 0; r < 4; ++r) {
            int m = row0 + wave * 32 + mt * 16 + quad * 4 + r;
            if (m >= M) continue;
            #pragma unroll
            for (int nt = 0; nt < 4; ++nt) {
                int n = col0 + nt * 16 + l15;
                float v = acc[mt][nt][r] + bias[n];
                if (RELU) v = fmaxf(v, 0.0f);
                if constexpr (sizeof(OutT) == 2)
                    out[(size_t)m * 256 + n] = (OutT)f2bf(v);
                else
                    out[(size_t)m * 256 + n] = (OutT)v;
            }
        }
    }
}

static inline size_t align_up(size_t v, size_t a) { return (v + a - 1) / a * a; }

extern "C" void kernel_launch(void* const* d_in, const int* in_sizes, int n_in,
                              void* d_out, int out_size, void* d_ws, size_t ws_size,
                              hipStream_t stream) {
    const float* x    = (const float*)d_in[0];
    const int*   ei   = (const int*)d_in[1];
    const float* W1_0 = (const float*)d_in[2];
    const float* W1_1 = (const float*)d_in[3];
    const float* b1   = (const float*)d_in[4];
    const float* W2_0 = (const float*)d_in[5];
    const float* W2_1 = (const float*)d_in[6];
    const float* b2   = (const float*)d_in[7];
    const float* W3_0 = (const float*)d_in[8];
    const float* W3_1 = (const float*)d_in[9];
    const float* b3   = (const float*)d_in[10];
    float* out = (float*)d_out;

    const int N = in_sizes[0] / 128;
    const int E = in_sizes[1] / 2;
    const int* src = ei;
    const int* dst = ei + E;

    typedef unsigned short u16;
    char* ws = (char*)d_ws;
    size_t off = 0;
    float* dinv   = (float*)(ws + off); off = align_up(off + (size_t)N * 4, 256);
    int*   cnt    = (int*)  (ws + off); off = align_up(off + (size_t)N * 4, 256);
    int*   rowptr = (int*)  (ws + off); off = align_up(off + (size_t)(N + 1) * 4, 256);
    int*   cursor = (int*)  (ws + off); off = align_up(off + (size_t)N * 4, 256);
    int*   part   = (int*)  (ws + off); off = align_up(off + 256 * 4, 256);
    int*   esrc   = (int*)  (ws + off); off = align_up(off + (size_t)E * 4, 256);
    float* ew     = (float*)(ws + off); off = align_up(off + (size_t)E * 4, 256);
    u16*   xb     = (u16*)  (ws + off); off = align_up(off + (size_t)N * 128 * 2, 256);
    u16*   txb    = (u16*)  (ws + off); off = align_up(off + (size_t)N * 256 * 2, 256);
    u16*   h1b    = (u16*)  (ws + off); off = align_up(off + (size_t)N * 256 * 2, 256);
    u16*   h2b    = (u16*)  (ws + off); off = align_up(off + (size_t)N * 256 * 2, 256);
    u16*   W10T   = (u16*)  (ws + off); off = align_up(off + (size_t)256 * 128 * 2, 256);
    u16*   W11T   = (u16*)  (ws + off); off = align_up(off + (size_t)256 * 128 * 2, 256);
    u16*   W20T   = (u16*)  (ws + off); off = align_up(off + (size_t)256 * 256 * 2, 256);
    u16*   W21T   = (u16*)  (ws + off); off = align_up(off + (size_t)256 * 256 * 2, 256);
    u16*   W30T   = (u16*)  (ws + off); off = align_up(off + (size_t)256 * 256 * 2, 256);
    u16*   W31T   = (u16*)  (ws + off); off = align_up(off + (size_t)256 * 256 * 2, 256);
    (void)ws_size;

    const int TB = 256;
    dim3 gE((E + TB - 1) / TB);
    dim3 gN((N + TB - 1) / TB);
    const int NB = (N + 1023) / 1024;

    // ---- norm + CSR build ----
    hipMemsetAsync(dinv, 0, (size_t)N * 4, stream);
    hipMemsetAsync(cnt, 0, (size_t)N * 4, stream);
    deg_cnt_kernel<<<gE, TB, 0, stream>>>(src, dst, dinv, cnt, E);
    dinv_kernel<<<gN, TB, 0, stream>>>(dinv, N);
    scan_partial<<<NB, 256, 0, stream>>>(cnt, part, N);
    scan_small<<<1, 64, 0, stream>>>(part, NB, rowptr, N);
    scan_chunk<<<NB, 256, 0, stream>>>(cnt, part, rowptr, N);
    hipMemcpyAsync(cursor, rowptr, (size_t)N * 4, hipMemcpyDeviceToDevice, stream);
    fill_kernel<<<gE, TB, 0, stream>>>(src, dst, dinv, cursor, esrc, ew, E);

    // ---- prep casts ----
    {
        long long n4 = (long long)N * 128 / 4;
        cast_x_kernel<<<(unsigned)((n4 + 255) / 256), TB, 0, stream>>>(x, xb, n4);
    }
    transpose_cast<<<dim3(4, 8), TB, 0, stream>>>(W1_0, W10T, 128);
    transpose_cast<<<dim3(4, 8), TB, 0, stream>>>(W1_1, W11T, 128);
    transpose_cast<<<dim3(8, 8), TB, 0, stream>>>(W2_0, W20T, 256);
    transpose_cast<<<dim3(8, 8), TB, 0, stream>>>(W2_1, W21T, 256);
    transpose_cast<<<dim3(8, 8), TB, 0, stream>>>(W3_0, W30T, 256);
    transpose_cast<<<dim3(8, 8), TB, 0, stream>>>(W3_1, W31T, 256);

    dim3 gemmGrid((N + 127) / 128, 4);
    dim3 gatherGrid((N + 3) / 4);

    // ---- layer 1: F=128 ----
    gather_bf16<128><<<gatherGrid, TB, 0, stream>>>(rowptr, esrc, ew, xb, txb, N);
    gemm_mfma<128, true, u16><<<gemmGrid, TB, 0, stream>>>(xb, txb, W10T, W11T, b1, h1b, N);

    // ---- layer 2: F=256 ----
    gather_bf16<256><<<gatherGrid, TB, 0, stream>>>(rowptr, esrc, ew, h1b, txb, N);
    gemm_mfma<256, true, u16><<<gemmGrid, TB, 0, stream>>>(h1b, txb, W20T, W21T, b2, h2b, N);

    // ---- layer 3: F=256, no relu, fp32 out ----
    gather_bf16<256><<<gatherGrid, TB, 0, stream>>>(rowptr, esrc, ew, h2b, txb, N);
    gemm_mfma<256, false, float><<<gemmGrid, TB, 0, stream>>>(h2b, txb, W30T, W31T, b3, out, N);
}

// Round 4
// 372.017 us; speedup vs baseline: 4.0573x; 1.0806x over previous
//
#include <hip/hip_runtime.h>
#include <hip/hip_bf16.h>

// ---------------------------------------------------------------------------
// GraphChebNet: 3-layer ChebConv (K=2), N=50000, E=400000.
// Round 4: GEMM BN=256 (full output width per block, 64-row tiles) so A/T are
// fetched from HBM exactly once (round-3 grid.y=4 re-read them 4x -> 101 MB
// fetch, pure traffic limit). Wave micro-tile 4x4 MFMA tiles. Batched weight
// transpose (1 launch), merged memsets. Gather / CSR build unchanged.
// ---------------------------------------------------------------------------

typedef __attribute__((ext_vector_type(8))) short bf16x8;
typedef __attribute__((ext_vector_type(4))) float f32x4;

__device__ __forceinline__ float bf2f(unsigned int lo16) {
    unsigned int t = lo16 << 16;
    return __builtin_bit_cast(float, t);
}
__device__ __forceinline__ unsigned short f2bf(float f) {
    unsigned int u = __builtin_bit_cast(unsigned int, f);
    unsigned int r = (u + 0x7fffu + ((u >> 16) & 1u)) >> 16;   // RNE
    return (unsigned short)r;
}

// ---------------- norm + CSR build ----------------
__global__ __launch_bounds__(256) void deg_cnt_kernel(const int* __restrict__ src,
                                                      const int* __restrict__ dst,
                                                      float* __restrict__ deg,
                                                      int* __restrict__ cnt, int E) {
    int e = blockIdx.x * blockDim.x + threadIdx.x;
    if (e < E) {
        int s = src[e], d = dst[e];
        if (s != d) atomicAdd(&deg[s], 1.0f);
        atomicAdd(&cnt[d], 1);
    }
}

__global__ __launch_bounds__(256) void dinv_kernel(float* __restrict__ deg, int N) {
    int i = blockIdx.x * blockDim.x + threadIdx.x;
    if (i < N) {
        float d = deg[i];
        deg[i] = (d > 0.0f) ? rsqrtf(d) : 0.0f;
    }
}

__global__ __launch_bounds__(256) void scan_partial(const int* __restrict__ cnt,
                                                    int* __restrict__ part, int N) {
    __shared__ int lds[256];
    int tid = threadIdx.x;
    int base = blockIdx.x * 1024 + tid * 4;
    int s = 0;
    #pragma unroll
    for (int i = 0; i < 4; ++i) if (base + i < N) s += cnt[base + i];
    lds[tid] = s;
    __syncthreads();
    for (int off = 128; off > 0; off >>= 1) {
        if (tid < off) lds[tid] += lds[tid + off];
        __syncthreads();
    }
    if (tid == 0) part[blockIdx.x] = lds[0];
}

__global__ __launch_bounds__(64) void scan_small(int* __restrict__ part, int NB,
                                                 int* __restrict__ rowptr, int N) {
    if (threadIdx.x == 0 && blockIdx.x == 0) {
        int total = 0;
        for (int i = 0; i < NB; ++i) { int t = part[i]; part[i] = total; total += t; }
        rowptr[N] = total;
    }
}

__global__ __launch_bounds__(256) void scan_chunk(const int* __restrict__ cnt,
                                                  const int* __restrict__ part,
                                                  int* __restrict__ rowptr, int N) {
    __shared__ int lds[256];
    int tid = threadIdx.x;
    int base = blockIdx.x * 1024 + tid * 4;
    int c[4];
    #pragma unroll
    for (int i = 0; i < 4; ++i) c[i] = (base + i < N) ? cnt[base + i] : 0;
    int ts = c[0] + c[1] + c[2] + c[3];
    lds[tid] = ts;
    __syncthreads();
    for (int off = 1; off < 256; off <<= 1) {
        int v = (tid >= off) ? lds[tid - off] : 0;
        __syncthreads();
        lds[tid] += v;
        __syncthreads();
    }
    int o = part[blockIdx.x] + lds[tid] - ts;
    #pragma unroll
    for (int i = 0; i < 4; ++i) {
        if (base + i < N) rowptr[base + i] = o;
        o += c[i];
    }
}

__global__ __launch_bounds__(256) void fill_kernel(const int* __restrict__ src,
                                                   const int* __restrict__ dst,
                                                   const float* __restrict__ dinv,
                                                   int* __restrict__ cursor,
                                                   int* __restrict__ esrc,
                                                   float* __restrict__ ew, int E) {
    int e = blockIdx.x * blockDim.x + threadIdx.x;
    if (e < E) {
        int s = src[e], d = dst[e];
        int pos = atomicAdd(&cursor[d], 1);
        esrc[pos] = s;
        ew[pos] = (s != d) ? (-dinv[s] * dinv[d]) : 0.0f;
    }
}

// ---------------- prep: casts ----------------
__global__ __launch_bounds__(256) void cast_x_kernel(const float* __restrict__ x,
                                                     unsigned short* __restrict__ xb,
                                                     long long n4) {
    long long i = (long long)blockIdx.x * 256 + threadIdx.x;
    if (i >= n4) return;
    float4 v = reinterpret_cast<const float4*>(x)[i];
    ushort4 o;
    o.x = f2bf(v.x); o.y = f2bf(v.y); o.z = f2bf(v.z); o.w = f2bf(v.w);
    reinterpret_cast<ushort4*>(xb)[i] = o;
}

// batched: W [K,256] fp32 -> WT [256,K] bf16, 6 matrices in one launch
struct TParams {
    const float* W[6];
    unsigned short* WT[6];
    int K[6];
};
__global__ __launch_bounds__(256) void transpose_cast_all(TParams p) {
    int m = blockIdx.z;
    int K = p.K[m];
    int kb = blockIdx.x * 32, nb = blockIdx.y * 32;
    if (kb >= K) return;
    const float* W = p.W[m];
    unsigned short* WT = p.WT[m];
    __shared__ float t[32][33];
    int lx = threadIdx.x & 31, ly = threadIdx.x >> 5;   // 32 x 8
    #pragma unroll
    for (int i = 0; i < 32; i += 8)
        t[ly + i][lx] = W[(size_t)(kb + ly + i) * 256 + nb + lx];
    __syncthreads();
    #pragma unroll
    for (int i = 0; i < 32; i += 8)
        WT[(size_t)(nb + ly + i) * K + kb + lx] = f2bf(t[lx][ly + i]);
}

// ---------------- gather: tx[n,:] = sum_e w_e * x[src_e,:], bf16 ----------------
template <int F>
__global__ __launch_bounds__(256) void gather_bf16(const int* __restrict__ rowptr,
                                                   const int* __restrict__ esrc,
                                                   const float* __restrict__ ew,
                                                   const unsigned short* __restrict__ xb,
                                                   unsigned short* __restrict__ txb,
                                                   int N) {
    constexpr int V = F / 64;   // 2 or 4
    int wave = threadIdx.x >> 6, lane = threadIdx.x & 63;
    int n = blockIdx.x * 4 + wave;
    if (n >= N) return;
    int beg = rowptr[n], end = rowptr[n + 1];
    float acc[V] = {};
    int s_next = 0; float w_next = 0.0f;
    if (beg < end) { s_next = esrc[beg]; w_next = ew[beg]; }
    for (int k = beg; k < end; ++k) {
        int s = s_next; float wv = w_next;
        if (k + 1 < end) { s_next = esrc[k + 1]; w_next = ew[k + 1]; }
        const unsigned short* p = &xb[(size_t)s * F + lane * V];
        if (V == 2) {
            unsigned int u = *reinterpret_cast<const unsigned int*>(p);
            acc[0] += wv * bf2f(u & 0xffffu);
            acc[1] += wv * bf2f(u >> 16);
        } else {
            uint2 u = *reinterpret_cast<const uint2*>(p);
            acc[0] += wv * bf2f(u.x & 0xffffu);
            acc[1] += wv * bf2f(u.x >> 16);
            acc[2] += wv * bf2f(u.y & 0xffffu);
            acc[3] += wv * bf2f(u.y >> 16);
        }
    }
    unsigned short* q = &txb[(size_t)n * F + lane * V];
    if (V == 2) {
        unsigned int o = (unsigned int)f2bf(acc[0]) | ((unsigned int)f2bf(acc[1]) << 16);
        *reinterpret_cast<unsigned int*>(q) = o;
    } else {
        uint2 o;
        o.x = (unsigned int)f2bf(acc[0]) | ((unsigned int)f2bf(acc[1]) << 16);
        o.y = (unsigned int)f2bf(acc[2]) | ((unsigned int)f2bf(acc[3]) << 16);
        *reinterpret_cast<uint2*>(q) = o;
    }
}

// ---------------- MFMA GEMM, BN=256 ----------------
// out[M,256] = relu?( Xb[M,K]@W0 + Tb[M,K]@W1 + b ), weights as WT[n][k] bf16.
// Block: 64 rows x 256 cols, 256 threads = 4 waves. Wave w covers all 64 rows
// (mt=0..3) x cols [w*64, w*64+64) (nt=0..3). BK=64. A/T fetched once per layer.
template <int K, bool RELU, typename OutT>
__global__ __launch_bounds__(256, 3) void gemm_mfma(const unsigned short* __restrict__ Xb,
                                                    const unsigned short* __restrict__ Tb,
                                                    const unsigned short* __restrict__ W0T,
                                                    const unsigned short* __restrict__ W1T,
                                                    const float* __restrict__ bias,
                                                    OutT* __restrict__ out, int M) {
    constexpr int SA = 72;   // LDS row stride (shorts): 2-way bank alias = free
    __shared__ unsigned short As[64 * SA];
    __shared__ unsigned short Bs[256 * SA];

    const int tid = threadIdx.x;
    const int wave = tid >> 6;
    const int lane = tid & 63;
    const int l15 = lane & 15;
    const int quad = lane >> 4;
    const int row0 = blockIdx.x * 64;

    // staging mapping: per 256-thread round, 32 rows x 64 k, uint4 (8 bf16)
    const int srow = tid >> 3;          // 0..31
    const int scol = (tid & 7) * 8;     // 0..56

    f32x4 acc[4][4];
    #pragma unroll
    for (int i = 0; i < 4; ++i)
        #pragma unroll
        for (int j = 0; j < 4; ++j) acc[i][j] = (f32x4){0.f, 0.f, 0.f, 0.f};

    #pragma unroll
    for (int pass = 0; pass < 2; ++pass) {
        const unsigned short* Amat = pass ? Tb : Xb;
        const unsigned short* Wmat = pass ? W1T : W0T;
        for (int k0 = 0; k0 < K; k0 += 64) {
            if (pass != 0 || k0 != 0) __syncthreads();
            // stage A: 64 rows x 64 k -> 2 rounds
            #pragma unroll
            for (int r = 0; r < 2; ++r) {
                int row = r * 32 + srow;
                int grow = row0 + row; if (grow > M - 1) grow = M - 1;
                uint4 v = *reinterpret_cast<const uint4*>(&Amat[(size_t)grow * K + k0 + scol]);
                *reinterpret_cast<uint4*>(&As[row * SA + scol]) = v;
            }
            // stage B: 256 cols x 64 k -> 8 rounds
            #pragma unroll
            for (int r = 0; r < 8; ++r) {
                int row = r * 32 + srow;
                uint4 v = *reinterpret_cast<const uint4*>(&Wmat[(size_t)row * K + k0 + scol]);
                *reinterpret_cast<uint4*>(&Bs[row * SA + scol]) = v;
            }
            __syncthreads();

            #pragma unroll
            for (int kf = 0; kf < 2; ++kf) {
                const int koff = kf * 32 + quad * 8;
                bf16x8 a[4], b[4];
                #pragma unroll
                for (int mt = 0; mt < 4; ++mt)
                    a[mt] = *reinterpret_cast<const bf16x8*>(&As[(mt * 16 + l15) * SA + koff]);
                #pragma unroll
                for (int nt = 0; nt < 4; ++nt)
                    b[nt] = *reinterpret_cast<const bf16x8*>(
                        &Bs[(wave * 64 + nt * 16 + l15) * SA + koff]);
                #pragma unroll
                for (int mt = 0; mt < 4; ++mt)
                    #pragma unroll
                    for (int nt = 0; nt < 4; ++nt)
                        acc[mt][nt] = __builtin_amdgcn_mfma_f32_16x16x32_bf16(
                            a[mt], b[nt], acc[mt][nt], 0, 0, 0);
            }
        }
    }

    // epilogue: C/D layout col=lane&15, row=quad*4+reg
    #pragma unroll
    for (int mt = 0; mt < 4; ++mt) {
        #pragma unroll
        for (int r = 0; r < 4; ++r) {
            int m = row0 + mt * 16 + quad * 4 + r;
            if (m >= M) continue;
            #pragma unroll
            for (int nt = 0; nt < 4; ++nt) {
                int n = wave * 64 + nt * 16 + l15;
                float v = acc[mt][nt][r] + bias[n];
                if (RELU) v = fmaxf(v, 0.0f);
                if constexpr (sizeof(OutT) == 2)
                    out[(size_t)m * 256 + n] = (OutT)f2bf(v);
                else
                    out[(size_t)m * 256 + n] = (OutT)v;
            }
        }
    }
}

static inline size_t align_up(size_t v, size_t a) { return (v + a - 1) / a * a; }

extern "C" void kernel_launch(void* const* d_in, const int* in_sizes, int n_in,
                              void* d_out, int out_size, void* d_ws, size_t ws_size,
                              hipStream_t stream) {
    const float* x    = (const float*)d_in[0];
    const int*   ei   = (const int*)d_in[1];
    const float* W1_0 = (const float*)d_in[2];
    const float* W1_1 = (const float*)d_in[3];
    const float* b1   = (const float*)d_in[4];
    const float* W2_0 = (const float*)d_in[5];
    const float* W2_1 = (const float*)d_in[6];
    const float* b2   = (const float*)d_in[7];
    const float* W3_0 = (const float*)d_in[8];
    const float* W3_1 = (const float*)d_in[9];
    const float* b3   = (const float*)d_in[10];
    float* out = (float*)d_out;

    const int N = in_sizes[0] / 128;
    const int E = in_sizes[1] / 2;
    const int* src = ei;
    const int* dst = ei + E;

    typedef unsigned short u16;
    char* ws = (char*)d_ws;
    size_t off = 0;
    float* dinv   = (float*)(ws + off); off = align_up(off + (size_t)N * 4, 256);
    int*   cnt    = (int*)  (ws + off); off = align_up(off + (size_t)N * 4, 256);
    size_t zero_end = off;                       // memset dinv..cnt in one shot
    int*   rowptr = (int*)  (ws + off); off = align_up(off + (size_t)(N + 1) * 4, 256);
    int*   cursor = (int*)  (ws + off); off = align_up(off + (size_t)N * 4, 256);
    int*   part   = (int*)  (ws + off); off = align_up(off + 256 * 4, 256);
    int*   esrc   = (int*)  (ws + off); off = align_up(off + (size_t)E * 4, 256);
    float* ew     = (float*)(ws + off); off = align_up(off + (size_t)E * 4, 256);
    u16*   xb     = (u16*)  (ws + off); off = align_up(off + (size_t)N * 128 * 2, 256);
    u16*   txb    = (u16*)  (ws + off); off = align_up(off + (size_t)N * 256 * 2, 256);
    u16*   h1b    = (u16*)  (ws + off); off = align_up(off + (size_t)N * 256 * 2, 256);
    u16*   h2b    = (u16*)  (ws + off); off = align_up(off + (size_t)N * 256 * 2, 256);
    u16*   W10T   = (u16*)  (ws + off); off = align_up(off + (size_t)256 * 128 * 2, 256);
    u16*   W11T   = (u16*)  (ws + off); off = align_up(off + (size_t)256 * 128 * 2, 256);
    u16*   W20T   = (u16*)  (ws + off); off = align_up(off + (size_t)256 * 256 * 2, 256);
    u16*   W21T   = (u16*)  (ws + off); off = align_up(off + (size_t)256 * 256 * 2, 256);
    u16*   W30T   = (u16*)  (ws + off); off = align_up(off + (size_t)256 * 256 * 2, 256);
    u16*   W31T   = (u16*)  (ws + off); off = align_up(off + (size_t)256 * 256 * 2, 256);
    (void)ws_size;

    const int TB = 256;
    dim3 gE((E + TB - 1) / TB);
    dim3 gN((N + TB - 1) / TB);
    const int NB = (N + 1023) / 1024;

    // ---- norm + CSR build ----
    hipMemsetAsync(dinv, 0, zero_end, stream);
    deg_cnt_kernel<<<gE, TB, 0, stream>>>(src, dst, dinv, cnt, E);
    dinv_kernel<<<gN, TB, 0, stream>>>(dinv, N);
    scan_partial<<<NB, 256, 0, stream>>>(cnt, part, N);
    scan_small<<<1, 64, 0, stream>>>(part, NB, rowptr, N);
    scan_chunk<<<NB, 256, 0, stream>>>(cnt, part, rowptr, N);
    hipMemcpyAsync(cursor, rowptr, (size_t)N * 4, hipMemcpyDeviceToDevice, stream);
    fill_kernel<<<gE, TB, 0, stream>>>(src, dst, dinv, cursor, esrc, ew, E);

    // ---- prep casts ----
    {
        long long n4 = (long long)N * 128 / 4;
        cast_x_kernel<<<(unsigned)((n4 + 255) / 256), TB, 0, stream>>>(x, xb, n4);
    }
    {
        TParams p;
        p.W[0] = W1_0; p.WT[0] = W10T; p.K[0] = 128;
        p.W[1] = W1_1; p.WT[1] = W11T; p.K[1] = 128;
        p.W[2] = W2_0; p.WT[2] = W20T; p.K[2] = 256;
        p.W[3] = W2_1; p.WT[3] = W21T; p.K[3] = 256;
        p.W[4] = W3_0; p.WT[4] = W30T; p.K[4] = 256;
        p.W[5] = W3_1; p.WT[5] = W31T; p.K[5] = 256;
        transpose_cast_all<<<dim3(8, 8, 6), TB, 0, stream>>>(p);
    }

    dim3 gemmGrid((N + 63) / 64);
    dim3 gatherGrid((N + 3) / 4);

    // ---- layer 1: F=128 ----
    gather_bf16<128><<<gatherGrid, TB, 0, stream>>>(rowptr, esrc, ew, xb, txb, N);
    gemm_mfma<128, true, u16><<<gemmGrid, TB, 0, stream>>>(xb, txb, W10T, W11T, b1, h1b, N);

    // ---- layer 2: F=256 ----
    gather_bf16<256><<<gatherGrid, TB, 0, stream>>>(rowptr, esrc, ew, h1b, txb, N);
    gemm_mfma<256, true, u16><<<gemmGrid, TB, 0, stream>>>(h1b, txb, W20T, W21T, b2, h2b, N);

    // ---- layer 3: F=256, no relu, fp32 out ----
    gather_bf16<256><<<gatherGrid, TB, 0, stream>>>(rowptr, esrc, ew, h2b, txb, N);
    gemm_mfma<256, false, float><<<gemmGrid, TB, 0, stream>>>(h2b, txb, W30T, W31T, b3, out, N);
}